// Round 14
// baseline (322.415 us; speedup 1.0000x reference)
//
#include <hip/hip_runtime.h>
#include <hip/hip_bf16.h>

#define BSH 9
#define BSZ 512    // nodes per bucket
#define CAP 17408  // edge capacity per bucket (mean 16384 + 8 sigma)
#define CHK 4096   // edges per scatter block (16 per thread)

__device__ __forceinline__ unsigned short f2bf(float f) {  // RN-even fp32->bf16
    unsigned u = __float_as_uint(f);
    u += 0x7fffu + ((u >> 16) & 1u);
    return (unsigned short)(u >> 16);
}
__device__ __forceinline__ float b2f(unsigned short v) {
    return __uint_as_float((unsigned)v << 16);
}

// init bucket cursors to fixed bases
__global__ void init_k(int* __restrict__ curD, int* __restrict__ curS, int nbk) {
    int i = threadIdx.x;
    if (i < nbk) { curD[i] = i * CAP; curS[i] = i * CAP; }
}

// ---------------- fused: GEMM1 (128 rows/block, wave-uniform col-half) + scatter ------------
// blocks [0, nG1): gemm.  blocks [nG1, nG1+NBLK): scatter.
// pairs packed: (src << 9) | (dst & 511).  sbuf: low 9 bits of src (ushort).

#define KCH 32
#define XTS 130  // [32][130] tile: reads 2-way (free), writes 2-way (free)

__global__ __launch_bounds__(256) void fused_gs_k(
    const float* __restrict__ X, const float* __restrict__ W, const float* __restrict__ B,
    float* __restrict__ H, int n, int nG1,
    const int* __restrict__ src, const int* __restrict__ dst, int E,
    int* __restrict__ curD, int* __restrict__ curS,
    unsigned int* __restrict__ pairs, unsigned short* __restrict__ sbuf, int nbk) {
    __shared__ char smem[33024];   // union: gemm tile (16.6 KB) | scatter stage (33 KB)
    int t = threadIdx.x;

    if ((int)blockIdx.x < nG1) {
        // ---- GEMM path: 128 rows, thread = (row r, wave-uniform col-half colh) ----
        float* xt = (float*)smem;
        int rowBase = blockIdx.x * 128;
        int r = t & 127, colh = t >> 7;        // colh wave-uniform (waves 0,1 -> 0; 2,3 -> 1)
        int srow = t >> 1, shalf = t & 1;      // staging: row, 16-float half of 32-k chunk
        int myRow = rowBase + r;

        float acc[8];
#pragma unroll
        for (int c = 0; c < 8; c++) acc[c] = 0.f;

        int sgr = rowBase + srow;
        const float* xrow = &X[(size_t)(sgr < n ? sgr : n - 1) * 512 + shalf * 16];
        float4 xreg[4];
#pragma unroll
        for (int p = 0; p < 4; p++) xreg[p] = *(const float4*)&xrow[p * 4];

        for (int ch = 0; ch < 16; ++ch) {
            int kb = shalf * 16;
#pragma unroll
            for (int p = 0; p < 4; p++) {
                xt[(kb + p * 4 + 0) * XTS + srow] = xreg[p].x;
                xt[(kb + p * 4 + 1) * XTS + srow] = xreg[p].y;
                xt[(kb + p * 4 + 2) * XTS + srow] = xreg[p].z;
                xt[(kb + p * 4 + 3) * XTS + srow] = xreg[p].w;
            }
            __syncthreads();

            if (ch < 15) {
#pragma unroll
                for (int p = 0; p < 4; p++)
                    xreg[p] = *(const float4*)&xrow[(ch + 1) * 32 + p * 4];
            }

#pragma unroll
            for (int k = 0; k < KCH; k++) {
                float xv = xt[k * XTS + r];
                // wave-uniform address -> scalar loads (SMEM pipe), 8 floats
                const float4* wr = (const float4*)&W[(size_t)(ch * KCH + k) * 16 + colh * 8];
                float4 w0 = wr[0], w1 = wr[1];
                acc[0] = fmaf(xv, w0.x, acc[0]); acc[1] = fmaf(xv, w0.y, acc[1]);
                acc[2] = fmaf(xv, w0.z, acc[2]); acc[3] = fmaf(xv, w0.w, acc[3]);
                acc[4] = fmaf(xv, w1.x, acc[4]); acc[5] = fmaf(xv, w1.y, acc[5]);
                acc[6] = fmaf(xv, w1.z, acc[6]); acc[7] = fmaf(xv, w1.w, acc[7]);
            }
            __syncthreads();
        }

        if (myRow < n) {
            const float4* bp = (const float4*)&B[colh * 8];
            float4 b0 = bp[0], b1 = bp[1];
            float4* o = (float4*)&H[(size_t)myRow * 16 + colh * 8];
            o[0] = float4{acc[0] + b0.x, acc[1] + b0.y, acc[2] + b0.z, acc[3] + b0.w};
            o[1] = float4{acc[4] + b1.x, acc[5] + b1.y, acc[6] + b1.z, acc[7] + b1.w};
        }
    } else {
        // ---- scatter path: register-batched LDS bucket sort -> coalesced burst writes ----
        unsigned int*   stageD = (unsigned int*)smem;             // 4096 * 4B
        unsigned short* stageS = (unsigned short*)(smem + 16384); // 4096 * 2B
        int* cntD  = (int*)(smem + 24576);
        int* cntS  = (int*)(smem + 25600);
        int* rsvD  = (int*)(smem + 26624);
        int* rsvS  = (int*)(smem + 27648);
        int* scanD = (int*)(smem + 28672);
        int* scanS = (int*)(smem + 29696);
        int* ps    = (int*)(smem + 30720);

        int bb = blockIdx.x - nG1;
        int lo = bb * CHK, hi = min(E, lo + CHK);
        bool full = (hi - lo) == CHK;

        cntD[t] = 0; cntS[t] = 0;
        __syncthreads();

        int sv[16], dv[16];
        if (full) {
#pragma unroll
            for (int j = 0; j < 16; j++) {
                int i = lo + t + j * 256;
                sv[j] = src[i]; dv[j] = dst[i];
            }
#pragma unroll
            for (int j = 0; j < 16; j++) {
                atomicAdd(&cntD[dv[j] >> BSH], 1);
                atomicAdd(&cntS[sv[j] >> BSH], 1);
            }
        } else {
            for (int i = lo + t; i < hi; i += 256) {
                atomicAdd(&cntD[dst[i] >> BSH], 1);
                atomicAdd(&cntS[src[i] >> BSH], 1);
            }
        }
        __syncthreads();
        int vD = cntD[t];
        ps[t] = vD; __syncthreads();
        for (int o = 1; o < 256; o <<= 1) {
            int u = (t >= o) ? ps[t - o] : 0; __syncthreads();
            ps[t] += u; __syncthreads();
        }
        scanD[t] = ps[t] - vD;
        if (t < nbk && vD) rsvD[t] = atomicAdd(&curD[t], vD);
        __syncthreads();
        int vS = cntS[t];
        ps[t] = vS; __syncthreads();
        for (int o = 1; o < 256; o <<= 1) {
            int u = (t >= o) ? ps[t - o] : 0; __syncthreads();
            ps[t] += u; __syncthreads();
        }
        scanS[t] = ps[t] - vS;
        if (t < nbk && vS) rsvS[t] = atomicAdd(&curS[t], vS);
        cntD[t] = 0; cntS[t] = 0;
        __syncthreads();
        if (full) {
#pragma unroll
            for (int j = 0; j < 16; j++) {
                int s = sv[j], d = dv[j];
                int bd = d >> BSH;
                int pd = scanD[bd] + atomicAdd(&cntD[bd], 1);
                stageD[pd] = ((unsigned int)s << BSH) | (unsigned int)(d & (BSZ - 1));
                int bs = s >> BSH;
                int pp = scanS[bs] + atomicAdd(&cntS[bs], 1);
                stageS[pp] = (unsigned short)(s & (BSZ - 1));
            }
        } else {
            for (int i = lo + t; i < hi; i += 256) {
                int s = src[i], d = dst[i];
                int bd = d >> BSH;
                int pd = scanD[bd] + atomicAdd(&cntD[bd], 1);
                stageD[pd] = ((unsigned int)s << BSH) | (unsigned int)(d & (BSZ - 1));
                int bs = s >> BSH;
                int pp = scanS[bs] + atomicAdd(&cntS[bs], 1);
                stageS[pp] = (unsigned short)(s & (BSZ - 1));
            }
        }
        __syncthreads();
        int wave = t >> 6, lane = t & 63;
        for (int b = wave; b < nbk; b += 4) {
            int st = scanD[b], len = cntD[b], g = rsvD[b];
            for (int j = lane; j < len; j += 64) pairs[g + j] = stageD[st + j];
        }
        for (int b = wave; b < nbk; b += 4) {
            int st = scanS[b], len = cntS[b], g = rsvS[b];
            for (int j = lane; j < len; j += 64) sbuf[g + j] = stageS[st + j];
        }
    }
}

// ---------------- dinv (src-degree) + scale h1 -> bf16 hw1 (hw1 = dinv * h1) ----------------

__global__ __launch_bounds__(256) void dinvScale_k(const unsigned short* __restrict__ sbuf,
                                                   const int* __restrict__ curS,
                                                   const float* __restrict__ h1,
                                                   float* __restrict__ dinv,
                                                   unsigned short* __restrict__ hw1, int n) {
    __shared__ int cnt[BSZ];
    __shared__ float dl[BSZ];
    int b = blockIdx.x, t = threadIdx.x;
    cnt[t] = 0; cnt[t + 256] = 0;
    __syncthreads();
    int lo = b * CAP, hi = curS[b];
    for (int i = lo + t; i < hi; i += 256) atomicAdd(&cnt[sbuf[i]], 1);
    __syncthreads();
    int n0 = b * BSZ + t, n1 = n0 + 256;
    float d0 = rsqrtf((float)(1 + cnt[t]));
    float d1 = rsqrtf((float)(1 + cnt[t + 256]));
    dl[t] = d0; dl[t + 256] = d1;
    if (n0 < n) dinv[n0] = d0;
    if (n1 < n) dinv[n1] = d1;
    __syncthreads();
    int rows = min(BSZ, n - b * BSZ);
    int lim4 = rows * 4;
    size_t base = (size_t)b * BSZ * 16;
#pragma unroll
    for (int j = 0; j < 8; j++) {
        int i4 = j * 256 + t;
        if (i4 < lim4) {
            float4 v = *(const float4*)&h1[base + (size_t)i4 * 4];
            float d = dl[i4 >> 2];
            ushort4 u;
            u.x = f2bf(v.x * d); u.y = f2bf(v.y * d);
            u.z = f2bf(v.z * d); u.w = f2bf(v.w * d);
            *(ushort4*)&hw1[base + (size_t)i4 * 4] = u;
        }
    }
}

// ---------------- CSR build + rowsum (fixed-point int atomics, NO fp-CAS) -------------------

__global__ __launch_bounds__(256) void build_k(const unsigned int* __restrict__ pairs,
                                               const int* __restrict__ curD,
                                               const float* __restrict__ dinv,
                                               int* __restrict__ rowPtr, int* __restrict__ cntD,
                                               int* __restrict__ col, float* __restrict__ rowsum,
                                               int n) {
    __shared__ int cnt[BSZ];
    __shared__ int off[BSZ];
    __shared__ int ps[256];
    __shared__ unsigned int lsum[BSZ];   // fixed-point 2^16
    int b = blockIdx.x, t = threadIdx.x;
    cnt[t] = 0; cnt[t + 256] = 0;
    lsum[t] = 0u; lsum[t + 256] = 0u;
    __syncthreads();
    int lo = b * CAP, hi = curD[b];
    for (int i = lo + t; i < hi; i += 256) atomicAdd(&cnt[pairs[i] & (BSZ - 1)], 1);
    __syncthreads();
    int c0 = cnt[2 * t], c1 = cnt[2 * t + 1];
    ps[t] = c0 + c1;
    __syncthreads();
    for (int o = 1; o < 256; o <<= 1) {
        int u = (t >= o) ? ps[t - o] : 0; __syncthreads();
        ps[t] += u; __syncthreads();
    }
    int ex = ps[t] - (c0 + c1);
    off[2 * t] = ex; off[2 * t + 1] = ex + c0;
    __syncthreads();
    int n0 = b * BSZ + t, n1 = n0 + 256;
    if (n0 < n) { rowPtr[n0] = lo + off[t]; cntD[n0] = cnt[t]; }
    if (n1 < n) { rowPtr[n1] = lo + off[t + 256]; cntD[n1] = cnt[t + 256]; }
    __syncthreads();
    cnt[t] = 0; cnt[t + 256] = 0;
    __syncthreads();
    for (int i = lo + t; i < hi; i += 256) {  // L2-hot re-read
        unsigned int p = pairs[i];
        int l = p & (BSZ - 1);
        int s = (int)(p >> BSH);
        int pos = lo + off[l] + atomicAdd(&cnt[l], 1);
        col[pos] = s;
        atomicAdd(&lsum[l], (unsigned int)(dinv[s] * 65536.f + 0.5f));
    }
    __syncthreads();
    const float inv = 1.f / 65536.f;
    if (n0 < n) { float dd = dinv[n0]; rowsum[n0] = dd * (dd + (float)lsum[t] * inv); }
    if (n1 < n) { float dd = dinv[n1]; rowsum[n1] = dd * (dd + (float)lsum[t + 256] * inv); }
}

// ---------------- aggregation on premultiplied bf16 features ----------------
// A[d] = hw[d] + sum_s hw[s];  4 lanes/edge, ushort4 (8B) per lane, 2-way unroll

__device__ __forceinline__ float4 gather_agg(const unsigned short* __restrict__ HW,
                                             const int* __restrict__ col,
                                             int start, int c, int node, int eg, int q) {
    float4 a0 = {0.f, 0.f, 0.f, 0.f}, a1 = {0.f, 0.f, 0.f, 0.f};
    int i = eg;
    for (; i + 16 < c; i += 32) {
        int s0 = col[start + i];
        int s1 = col[start + i + 16];
        ushort4 u0 = *(const ushort4*)&HW[(size_t)s0 * 16 + q * 4];
        ushort4 u1 = *(const ushort4*)&HW[(size_t)s1 * 16 + q * 4];
        a0.x += b2f(u0.x); a0.y += b2f(u0.y); a0.z += b2f(u0.z); a0.w += b2f(u0.w);
        a1.x += b2f(u1.x); a1.y += b2f(u1.y); a1.z += b2f(u1.z); a1.w += b2f(u1.w);
    }
    if (i < c) {
        int s0 = col[start + i];
        ushort4 u0 = *(const ushort4*)&HW[(size_t)s0 * 16 + q * 4];
        a0.x += b2f(u0.x); a0.y += b2f(u0.y); a0.z += b2f(u0.z); a0.w += b2f(u0.w);
    }
    if (eg == 0) {  // self loop
        ushort4 us = *(const ushort4*)&HW[(size_t)node * 16 + q * 4];
        a1.x += b2f(us.x); a1.y += b2f(us.y); a1.z += b2f(us.z); a1.w += b2f(us.w);
    }
    a0.x += a1.x; a0.y += a1.y; a0.z += a1.z; a0.w += a1.w;
#pragma unroll
    for (int off = 4; off < 64; off <<= 1) {
        a0.x += __shfl_xor(a0.x, off, 64);
        a0.y += __shfl_xor(a0.y, off, 64);
        a0.z += __shfl_xor(a0.z, off, 64);
        a0.w += __shfl_xor(a0.w, off, 64);
    }
    return a0;
}

// layer-1: out = bf16( dinv * relu(dinv * A) )   (premultiplied for layer 2)
__global__ void agg1_k(const unsigned short* __restrict__ HW, const float* __restrict__ dinv,
                       const int* __restrict__ col, const int* __restrict__ rowPtr,
                       const int* __restrict__ cnt, unsigned short* __restrict__ out, int n) {
    int lane = threadIdx.x & 63;
    int node = (blockIdx.x * blockDim.x + threadIdx.x) >> 6;
    if (node >= n) return;
    int eg = lane >> 2, q = lane & 3;
    int start = rowPtr[node], c = cnt[node];
    float4 A = gather_agg(HW, col, start, c, node, eg, q);
    if (eg == 0) {
        float dd = dinv[node];
        ushort4 u;
        u.x = f2bf(dd * fmaxf(dd * A.x, 0.f)); u.y = f2bf(dd * fmaxf(dd * A.y, 0.f));
        u.z = f2bf(dd * fmaxf(dd * A.z, 0.f)); u.w = f2bf(dd * fmaxf(dd * A.w, 0.f));
        *(ushort4*)&out[(size_t)node * 16 + q * 4] = u;
    }
}

// layer-2 aggregation fused with logits + log_softmax
__global__ void agg2f_k(const unsigned short* __restrict__ HW, const float* __restrict__ dinv,
                        const int* __restrict__ col, const int* __restrict__ rowPtr,
                        const int* __restrict__ cnt, const float* __restrict__ rowsum,
                        const float* __restrict__ W2, const float* __restrict__ B2,
                        float* __restrict__ out, int n, int nc) {
    int lane = threadIdx.x & 63;
    int node = (blockIdx.x * blockDim.x + threadIdx.x) >> 6;
    if (node >= n) return;
    int eg = lane >> 2, q = lane & 3;
    int start = rowPtr[node], c = cnt[node];
    float4 A = gather_agg(HW, col, start, c, node, eg, q);
    float dd = dinv[node];
    A.x *= dd; A.y *= dd; A.z *= dd; A.w *= dd;
    float f[16];
    f[0]  = __shfl(A.x, 0, 64); f[1]  = __shfl(A.y, 0, 64);
    f[2]  = __shfl(A.z, 0, 64); f[3]  = __shfl(A.w, 0, 64);
    f[4]  = __shfl(A.x, 1, 64); f[5]  = __shfl(A.y, 1, 64);
    f[6]  = __shfl(A.z, 1, 64); f[7]  = __shfl(A.w, 1, 64);
    f[8]  = __shfl(A.x, 2, 64); f[9]  = __shfl(A.y, 2, 64);
    f[10] = __shfl(A.z, 2, 64); f[11] = __shfl(A.w, 2, 64);
    f[12] = __shfl(A.x, 3, 64); f[13] = __shfl(A.y, 3, 64);
    f[14] = __shfl(A.z, 3, 64); f[15] = __shfl(A.w, 3, 64);
    float logit = -1e30f;
    if (lane < nc) {
        logit = rowsum[node] * B2[lane];
#pragma unroll
        for (int k = 0; k < 16; k++) logit = fmaf(f[k], W2[k * nc + lane], logit);
    }
    float m = logit;
#pragma unroll
    for (int off = 1; off < 64; off <<= 1) m = fmaxf(m, __shfl_xor(m, off, 64));
    float e = (lane < nc) ? __expf(logit - m) : 0.f;
    float s = e;
#pragma unroll
    for (int off = 1; off < 64; off <<= 1) s += __shfl_xor(s, off, 64);
    if (lane < nc) out[(size_t)node * nc + lane] = logit - m - __logf(s);
}

// ---------------- launch ----------------

extern "C" void kernel_launch(void* const* d_in, const int* in_sizes, int n_in,
                              void* d_out, int out_size, void* d_ws, size_t ws_size,
                              hipStream_t stream) {
    const float* X  = (const float*)d_in[0];
    const int*   EI = (const int*)d_in[1];
    const float* W1 = (const float*)d_in[2];
    const float* B1 = (const float*)d_in[3];
    const float* W2 = (const float*)d_in[4];
    const float* B2 = (const float*)d_in[5];
    float* out = (float*)d_out;

    int NH = in_sizes[3];            // 16
    int NC = in_sizes[5];            // 40
    int NF = in_sizes[2] / NH;       // 512
    int n  = in_sizes[0] / NF;       // 100000
    int E  = in_sizes[1] / 2;        // 3200000
    const int* src = EI;
    const int* dst = EI + E;
    int nbk = (n + BSZ - 1) >> BSH;  // 196

    char* ws = (char*)d_ws;
    size_t o = 0;
    auto alloc = [&](size_t bytes) { size_t r = o; o = (o + bytes + 255) & ~(size_t)255; return r; };
    size_t o_dinv   = alloc((size_t)n * 4);
    size_t o_rowPtr = alloc((size_t)n * 4);
    size_t o_cntD   = alloc((size_t)n * 4);
    size_t o_rsum   = alloc((size_t)n * 4);
    size_t o_curD   = alloc(1024);
    size_t o_curS   = alloc(1024);
    size_t o_pairs  = alloc((size_t)nbk * CAP * 4);
    size_t o_sbuf   = alloc((size_t)nbk * CAP * 2);
    size_t o_col    = alloc((size_t)nbk * CAP * 4);
    size_t o_h1     = alloc((size_t)n * 16 * 4);
    size_t o_hw1    = alloc((size_t)n * 16 * 2);
    size_t o_a1w    = alloc((size_t)n * 16 * 2);

    float* dinv  = (float*)(ws + o_dinv);
    int* rowPtr  = (int*)(ws + o_rowPtr);
    int* cntD    = (int*)(ws + o_cntD);
    float* rsum  = (float*)(ws + o_rsum);
    int* curD    = (int*)(ws + o_curD);
    int* curS    = (int*)(ws + o_curS);
    unsigned int* pairs   = (unsigned int*)(ws + o_pairs);
    unsigned short* sbuf  = (unsigned short*)(ws + o_sbuf);
    int* col     = (int*)(ws + o_col);
    float* h1    = (float*)(ws + o_h1);
    unsigned short* hw1 = (unsigned short*)(ws + o_hw1);
    unsigned short* a1w = (unsigned short*)(ws + o_a1w);

    init_k<<<1, 256, 0, stream>>>(curD, curS, nbk);

    int NBLK = (E + CHK - 1) / CHK;   // 782
    int nG1 = (n + 127) / 128;        // 782
    fused_gs_k<<<nG1 + NBLK, 256, 0, stream>>>(X, W1, B1, h1, n, nG1,
                                               src, dst, E, curD, curS,
                                               pairs, sbuf, nbk);
    dinvScale_k<<<nbk, 256, 0, stream>>>(sbuf, curS, h1, dinv, hw1, n);
    build_k<<<nbk, 256, 0, stream>>>(pairs, curD, dinv, rowPtr, cntD, col, rsum, n);

    int aggGrid = (n + 3) / 4;
    agg1_k<<<aggGrid, 256, 0, stream>>>(hw1, dinv, col, rowPtr, cntD, a1w, n);
    agg2f_k<<<aggGrid, 256, 0, stream>>>(a1w, dinv, col, rowPtr, cntD, rsum, W2, B2, out, n, NC);
}

// Round 15
// 281.440 us; speedup vs baseline: 1.1456x; 1.1456x over previous
//
#include <hip/hip_runtime.h>
#include <hip/hip_bf16.h>

#define BSH 9
#define BSZ 512    // nodes per bucket
#define CAP 17408  // edge capacity per bucket (mean 16384 + 8 sigma)
#define CHK 4096   // edges per scatter block (16 per thread)

typedef __attribute__((ext_vector_type(8))) short bf16x8;
typedef __attribute__((ext_vector_type(4))) float f32x4;

__device__ __forceinline__ unsigned short f2bf(float f) {  // RN-even fp32->bf16
    unsigned u = __float_as_uint(f);
    u += 0x7fffu + ((u >> 16) & 1u);
    return (unsigned short)(u >> 16);
}
__device__ __forceinline__ float b2f(unsigned short v) {
    return __uint_as_float((unsigned)v << 16);
}

// init bucket cursors to fixed bases
__global__ void init_k(int* __restrict__ curD, int* __restrict__ curS, int nbk) {
    int i = threadIdx.x;
    if (i < nbk) { curD[i] = i * CAP; curS[i] = i * CAP; }
}

// ---------------- scatter: register-batched LDS bucket sort -> coalesced burst writes -------
// pairs packed: (src << 9) | (dst & 511).  sbuf: low 9 bits of src (ushort).

__global__ __launch_bounds__(256) void scatter_k(
    const int* __restrict__ src, const int* __restrict__ dst, int E,
    int* __restrict__ curD, int* __restrict__ curS,
    unsigned int* __restrict__ pairs, unsigned short* __restrict__ sbuf, int nbk) {
    __shared__ char smem[33024];
    unsigned int*   stageD = (unsigned int*)smem;             // 4096 * 4B
    unsigned short* stageS = (unsigned short*)(smem + 16384); // 4096 * 2B
    int* cntD  = (int*)(smem + 24576);
    int* cntS  = (int*)(smem + 25600);
    int* rsvD  = (int*)(smem + 26624);
    int* rsvS  = (int*)(smem + 27648);
    int* scanD = (int*)(smem + 28672);
    int* scanS = (int*)(smem + 29696);
    int* ps    = (int*)(smem + 30720);
    int t = threadIdx.x;

    int lo = blockIdx.x * CHK, hi = min(E, lo + CHK);
    bool full = (hi - lo) == CHK;

    cntD[t] = 0; cntS[t] = 0;
    __syncthreads();

    int sv[16], dv[16];
    if (full) {
#pragma unroll
        for (int j = 0; j < 16; j++) {
            int i = lo + t + j * 256;
            sv[j] = src[i]; dv[j] = dst[i];
        }
#pragma unroll
        for (int j = 0; j < 16; j++) {
            atomicAdd(&cntD[dv[j] >> BSH], 1);
            atomicAdd(&cntS[sv[j] >> BSH], 1);
        }
    } else {
        for (int i = lo + t; i < hi; i += 256) {
            atomicAdd(&cntD[dst[i] >> BSH], 1);
            atomicAdd(&cntS[src[i] >> BSH], 1);
        }
    }
    __syncthreads();
    int vD = cntD[t];
    ps[t] = vD; __syncthreads();
    for (int o = 1; o < 256; o <<= 1) {
        int u = (t >= o) ? ps[t - o] : 0; __syncthreads();
        ps[t] += u; __syncthreads();
    }
    scanD[t] = ps[t] - vD;
    if (t < nbk && vD) rsvD[t] = atomicAdd(&curD[t], vD);
    __syncthreads();
    int vS = cntS[t];
    ps[t] = vS; __syncthreads();
    for (int o = 1; o < 256; o <<= 1) {
        int u = (t >= o) ? ps[t - o] : 0; __syncthreads();
        ps[t] += u; __syncthreads();
    }
    scanS[t] = ps[t] - vS;
    if (t < nbk && vS) rsvS[t] = atomicAdd(&curS[t], vS);
    cntD[t] = 0; cntS[t] = 0;
    __syncthreads();
    if (full) {
#pragma unroll
        for (int j = 0; j < 16; j++) {
            int s = sv[j], d = dv[j];
            int bd = d >> BSH;
            int pd = scanD[bd] + atomicAdd(&cntD[bd], 1);
            stageD[pd] = ((unsigned int)s << BSH) | (unsigned int)(d & (BSZ - 1));
            int bs = s >> BSH;
            int pp = scanS[bs] + atomicAdd(&cntS[bs], 1);
            stageS[pp] = (unsigned short)(s & (BSZ - 1));
        }
    } else {
        for (int i = lo + t; i < hi; i += 256) {
            int s = src[i], d = dst[i];
            int bd = d >> BSH;
            int pd = scanD[bd] + atomicAdd(&cntD[bd], 1);
            stageD[pd] = ((unsigned int)s << BSH) | (unsigned int)(d & (BSZ - 1));
            int bs = s >> BSH;
            int pp = scanS[bs] + atomicAdd(&cntS[bs], 1);
            stageS[pp] = (unsigned short)(s & (BSZ - 1));
        }
    }
    __syncthreads();
    int wave = t >> 6, lane = t & 63;
    for (int b = wave; b < nbk; b += 4) {
        int st = scanD[b], len = cntD[b], g = rsvD[b];
        for (int j = lane; j < len; j += 64) pairs[g + j] = stageD[st + j];
    }
    for (int b = wave; b < nbk; b += 4) {
        int st = scanS[b], len = cntS[b], g = rsvS[b];
        for (int j = lane; j < len; j += 64) sbuf[g + j] = stageS[st + j];
    }
}

// ---------------- GEMM1 via bf16 MFMA: h1 = X@W1 + b1 ----------------
// 64 rows/block (4 waves x one 16-row tile), K chunked 2x256 through LDS (bf16),
// W1 bf16 B-frags resident in 64 VGPRs (loaded once).
// A-frag: row=lane&15, k=(lane>>4)*8+j (contiguous 8 bf16 = ds_read_b128).
// B-frag: col=lane&15, k=(lane>>4)*8+j.  C/D: col=lane&15, row=(lane>>4)*4+reg.

#define GROWS 64
#define GKC 256
#define GSTR 264   // bf16 row stride: 132 dwords == 4 mod 32 -> 2-way banks (free)

__global__ __launch_bounds__(256, 4) void gemm_mfma_k(
    const float* __restrict__ X, const float* __restrict__ W, const float* __restrict__ B,
    float* __restrict__ H, int n) {
    __shared__ unsigned short xt[GROWS * GSTR];   // 33.8 KB
    int t = threadIdx.x;
    int lane = t & 63, wave = t >> 6;
    int rowBase = blockIdx.x * GROWS;
    int bn = lane & 15, bkg = (lane >> 4) * 8;

    // B-frags: one-time load (W1 is 32KB, L1/L2-hot across blocks)
    bf16x8 bw[16];
#pragma unroll
    for (int kt = 0; kt < 16; ++kt) {
        bf16x8 v;
#pragma unroll
        for (int j = 0; j < 8; ++j)
            v[j] = (short)f2bf(W[(size_t)(kt * 32 + bkg + j) * 16 + bn]);
        bw[kt] = v;
    }
    float bias = B[bn];

    f32x4 acc = {0.f, 0.f, 0.f, 0.f};
    int srow = t >> 4, skq = t & 15;   // staging: 16 rows/pass, 16 lanes x float4 along k

    for (int ch = 0; ch < 2; ++ch) {
        // stage 64 rows x 256 k: fp32 -> bf16
#pragma unroll
        for (int p = 0; p < 4; ++p) {
            int r = p * 16 + srow;
            int gr = rowBase + r;
            const float* xr = &X[(size_t)(gr < n ? gr : n - 1) * 512 + ch * GKC + skq * 4];
#pragma unroll
            for (int q = 0; q < 4; ++q) {
                float4 v = *(const float4*)&xr[q * 64];
                ushort4 u;
                u.x = f2bf(v.x); u.y = f2bf(v.y); u.z = f2bf(v.z); u.w = f2bf(v.w);
                *(ushort4*)&xt[r * GSTR + skq * 4 + q * 64] = u;
            }
        }
        __syncthreads();

        int rb = (wave * 16 + bn) * GSTR + bkg;
#pragma unroll
        for (int kt = 0; kt < 8; ++kt) {
            bf16x8 af = *(const bf16x8*)&xt[rb + kt * 32];
            acc = __builtin_amdgcn_mfma_f32_16x16x32_bf16(af, bw[ch * 8 + kt], acc, 0, 0, 0);
        }
        __syncthreads();   // protect next chunk's staging
    }

    int r0 = rowBase + wave * 16 + (lane >> 4) * 4;
#pragma unroll
    for (int i = 0; i < 4; ++i) {
        int row = r0 + i;
        if (row < n) H[(size_t)row * 16 + bn] = acc[i] + bias;
    }
}

// ---------------- dinv (src-degree) + scale h1 -> bf16 hw1 (hw1 = dinv * h1) ----------------

__global__ __launch_bounds__(256) void dinvScale_k(const unsigned short* __restrict__ sbuf,
                                                   const int* __restrict__ curS,
                                                   const float* __restrict__ h1,
                                                   float* __restrict__ dinv,
                                                   unsigned short* __restrict__ hw1, int n) {
    __shared__ int cnt[BSZ];
    __shared__ float dl[BSZ];
    int b = blockIdx.x, t = threadIdx.x;
    cnt[t] = 0; cnt[t + 256] = 0;
    __syncthreads();
    int lo = b * CAP, hi = curS[b];
    for (int i = lo + t; i < hi; i += 256) atomicAdd(&cnt[sbuf[i]], 1);
    __syncthreads();
    int n0 = b * BSZ + t, n1 = n0 + 256;
    float d0 = rsqrtf((float)(1 + cnt[t]));
    float d1 = rsqrtf((float)(1 + cnt[t + 256]));
    dl[t] = d0; dl[t + 256] = d1;
    if (n0 < n) dinv[n0] = d0;
    if (n1 < n) dinv[n1] = d1;
    __syncthreads();
    int rows = min(BSZ, n - b * BSZ);
    int lim4 = rows * 4;
    size_t base = (size_t)b * BSZ * 16;
#pragma unroll
    for (int j = 0; j < 8; j++) {
        int i4 = j * 256 + t;
        if (i4 < lim4) {
            float4 v = *(const float4*)&h1[base + (size_t)i4 * 4];
            float d = dl[i4 >> 2];
            ushort4 u;
            u.x = f2bf(v.x * d); u.y = f2bf(v.y * d);
            u.z = f2bf(v.z * d); u.w = f2bf(v.w * d);
            *(ushort4*)&hw1[base + (size_t)i4 * 4] = u;
        }
    }
}

// ---------------- CSR build + rowsum (fixed-point int atomics, NO fp-CAS) -------------------

__global__ __launch_bounds__(256) void build_k(const unsigned int* __restrict__ pairs,
                                               const int* __restrict__ curD,
                                               const float* __restrict__ dinv,
                                               int* __restrict__ rowPtr, int* __restrict__ cntD,
                                               int* __restrict__ col, float* __restrict__ rowsum,
                                               int n) {
    __shared__ int cnt[BSZ];
    __shared__ int off[BSZ];
    __shared__ int ps[256];
    __shared__ unsigned int lsum[BSZ];   // fixed-point 2^16
    int b = blockIdx.x, t = threadIdx.x;
    cnt[t] = 0; cnt[t + 256] = 0;
    lsum[t] = 0u; lsum[t + 256] = 0u;
    __syncthreads();
    int lo = b * CAP, hi = curD[b];
    for (int i = lo + t; i < hi; i += 256) atomicAdd(&cnt[pairs[i] & (BSZ - 1)], 1);
    __syncthreads();
    int c0 = cnt[2 * t], c1 = cnt[2 * t + 1];
    ps[t] = c0 + c1;
    __syncthreads();
    for (int o = 1; o < 256; o <<= 1) {
        int u = (t >= o) ? ps[t - o] : 0; __syncthreads();
        ps[t] += u; __syncthreads();
    }
    int ex = ps[t] - (c0 + c1);
    off[2 * t] = ex; off[2 * t + 1] = ex + c0;
    __syncthreads();
    int n0 = b * BSZ + t, n1 = n0 + 256;
    if (n0 < n) { rowPtr[n0] = lo + off[t]; cntD[n0] = cnt[t]; }
    if (n1 < n) { rowPtr[n1] = lo + off[t + 256]; cntD[n1] = cnt[t + 256]; }
    __syncthreads();
    cnt[t] = 0; cnt[t + 256] = 0;
    __syncthreads();
    for (int i = lo + t; i < hi; i += 256) {  // L2-hot re-read
        unsigned int p = pairs[i];
        int l = p & (BSZ - 1);
        int s = (int)(p >> BSH);
        int pos = lo + off[l] + atomicAdd(&cnt[l], 1);
        col[pos] = s;
        atomicAdd(&lsum[l], (unsigned int)(dinv[s] * 65536.f + 0.5f));
    }
    __syncthreads();
    const float inv = 1.f / 65536.f;
    if (n0 < n) { float dd = dinv[n0]; rowsum[n0] = dd * (dd + (float)lsum[t] * inv); }
    if (n1 < n) { float dd = dinv[n1]; rowsum[n1] = dd * (dd + (float)lsum[t + 256] * inv); }
}

// ---------------- aggregation on premultiplied bf16 features ----------------

__device__ __forceinline__ float4 gather_agg(const unsigned short* __restrict__ HW,
                                             const int* __restrict__ col,
                                             int start, int c, int node, int eg, int q) {
    float4 a0 = {0.f, 0.f, 0.f, 0.f}, a1 = {0.f, 0.f, 0.f, 0.f};
    int i = eg;
    for (; i + 16 < c; i += 32) {
        int s0 = col[start + i];
        int s1 = col[start + i + 16];
        ushort4 u0 = *(const ushort4*)&HW[(size_t)s0 * 16 + q * 4];
        ushort4 u1 = *(const ushort4*)&HW[(size_t)s1 * 16 + q * 4];
        a0.x += b2f(u0.x); a0.y += b2f(u0.y); a0.z += b2f(u0.z); a0.w += b2f(u0.w);
        a1.x += b2f(u1.x); a1.y += b2f(u1.y); a1.z += b2f(u1.z); a1.w += b2f(u1.w);
    }
    if (i < c) {
        int s0 = col[start + i];
        ushort4 u0 = *(const ushort4*)&HW[(size_t)s0 * 16 + q * 4];
        a0.x += b2f(u0.x); a0.y += b2f(u0.y); a0.z += b2f(u0.z); a0.w += b2f(u0.w);
    }
    if (eg == 0) {  // self loop
        ushort4 us = *(const ushort4*)&HW[(size_t)node * 16 + q * 4];
        a1.x += b2f(us.x); a1.y += b2f(us.y); a1.z += b2f(us.z); a1.w += b2f(us.w);
    }
    a0.x += a1.x; a0.y += a1.y; a0.z += a1.z; a0.w += a1.w;
#pragma unroll
    for (int off = 4; off < 64; off <<= 1) {
        a0.x += __shfl_xor(a0.x, off, 64);
        a0.y += __shfl_xor(a0.y, off, 64);
        a0.z += __shfl_xor(a0.z, off, 64);
        a0.w += __shfl_xor(a0.w, off, 64);
    }
    return a0;
}

// layer-1: out = bf16( dinv * relu(dinv * A) )
__global__ void agg1_k(const unsigned short* __restrict__ HW, const float* __restrict__ dinv,
                       const int* __restrict__ col, const int* __restrict__ rowPtr,
                       const int* __restrict__ cnt, unsigned short* __restrict__ out, int n) {
    int lane = threadIdx.x & 63;
    int node = (blockIdx.x * blockDim.x + threadIdx.x) >> 6;
    if (node >= n) return;
    int eg = lane >> 2, q = lane & 3;
    int start = rowPtr[node], c = cnt[node];
    float4 A = gather_agg(HW, col, start, c, node, eg, q);
    if (eg == 0) {
        float dd = dinv[node];
        ushort4 u;
        u.x = f2bf(dd * fmaxf(dd * A.x, 0.f)); u.y = f2bf(dd * fmaxf(dd * A.y, 0.f));
        u.z = f2bf(dd * fmaxf(dd * A.z, 0.f)); u.w = f2bf(dd * fmaxf(dd * A.w, 0.f));
        *(ushort4*)&out[(size_t)node * 16 + q * 4] = u;
    }
}

// layer-2 aggregation fused with logits + log_softmax
__global__ void agg2f_k(const unsigned short* __restrict__ HW, const float* __restrict__ dinv,
                        const int* __restrict__ col, const int* __restrict__ rowPtr,
                        const int* __restrict__ cnt, const float* __restrict__ rowsum,
                        const float* __restrict__ W2, const float* __restrict__ B2,
                        float* __restrict__ out, int n, int nc) {
    int lane = threadIdx.x & 63;
    int node = (blockIdx.x * blockDim.x + threadIdx.x) >> 6;
    if (node >= n) return;
    int eg = lane >> 2, q = lane & 3;
    int start = rowPtr[node], c = cnt[node];
    float4 A = gather_agg(HW, col, start, c, node, eg, q);
    float dd = dinv[node];
    A.x *= dd; A.y *= dd; A.z *= dd; A.w *= dd;
    float f[16];
    f[0]  = __shfl(A.x, 0, 64); f[1]  = __shfl(A.y, 0, 64);
    f[2]  = __shfl(A.z, 0, 64); f[3]  = __shfl(A.w, 0, 64);
    f[4]  = __shfl(A.x, 1, 64); f[5]  = __shfl(A.y, 1, 64);
    f[6]  = __shfl(A.z, 1, 64); f[7]  = __shfl(A.w, 1, 64);
    f[8]  = __shfl(A.x, 2, 64); f[9]  = __shfl(A.y, 2, 64);
    f[10] = __shfl(A.z, 2, 64); f[11] = __shfl(A.w, 2, 64);
    f[12] = __shfl(A.x, 3, 64); f[13] = __shfl(A.y, 3, 64);
    f[14] = __shfl(A.z, 3, 64); f[15] = __shfl(A.w, 3, 64);
    float logit = -1e30f;
    if (lane < nc) {
        logit = rowsum[node] * B2[lane];
#pragma unroll
        for (int k = 0; k < 16; k++) logit = fmaf(f[k], W2[k * nc + lane], logit);
    }
    float m = logit;
#pragma unroll
    for (int off = 1; off < 64; off <<= 1) m = fmaxf(m, __shfl_xor(m, off, 64));
    float e = (lane < nc) ? __expf(logit - m) : 0.f;
    float s = e;
#pragma unroll
    for (int off = 1; off < 64; off <<= 1) s += __shfl_xor(s, off, 64);
    if (lane < nc) out[(size_t)node * nc + lane] = logit - m - __logf(s);
}

// ---------------- launch ----------------

extern "C" void kernel_launch(void* const* d_in, const int* in_sizes, int n_in,
                              void* d_out, int out_size, void* d_ws, size_t ws_size,
                              hipStream_t stream) {
    const float* X  = (const float*)d_in[0];
    const int*   EI = (const int*)d_in[1];
    const float* W1 = (const float*)d_in[2];
    const float* B1 = (const float*)d_in[3];
    const float* W2 = (const float*)d_in[4];
    const float* B2 = (const float*)d_in[5];
    float* out = (float*)d_out;

    int NH = in_sizes[3];            // 16
    int NC = in_sizes[5];            // 40
    int NF = in_sizes[2] / NH;       // 512
    int n  = in_sizes[0] / NF;       // 100000
    int E  = in_sizes[1] / 2;        // 3200000
    const int* src = EI;
    const int* dst = EI + E;
    int nbk = (n + BSZ - 1) >> BSH;  // 196

    char* ws = (char*)d_ws;
    size_t o = 0;
    auto alloc = [&](size_t bytes) { size_t r = o; o = (o + bytes + 255) & ~(size_t)255; return r; };
    size_t o_dinv   = alloc((size_t)n * 4);
    size_t o_rowPtr = alloc((size_t)n * 4);
    size_t o_cntD   = alloc((size_t)n * 4);
    size_t o_rsum   = alloc((size_t)n * 4);
    size_t o_curD   = alloc(1024);
    size_t o_curS   = alloc(1024);
    size_t o_pairs  = alloc((size_t)nbk * CAP * 4);
    size_t o_sbuf   = alloc((size_t)nbk * CAP * 2);
    size_t o_col    = alloc((size_t)nbk * CAP * 4);
    size_t o_h1     = alloc((size_t)n * 16 * 4);
    size_t o_hw1    = alloc((size_t)n * 16 * 2);
    size_t o_a1w    = alloc((size_t)n * 16 * 2);

    float* dinv  = (float*)(ws + o_dinv);
    int* rowPtr  = (int*)(ws + o_rowPtr);
    int* cntD    = (int*)(ws + o_cntD);
    float* rsum  = (float*)(ws + o_rsum);
    int* curD    = (int*)(ws + o_curD);
    int* curS    = (int*)(ws + o_curS);
    unsigned int* pairs   = (unsigned int*)(ws + o_pairs);
    unsigned short* sbuf  = (unsigned short*)(ws + o_sbuf);
    int* col     = (int*)(ws + o_col);
    float* h1    = (float*)(ws + o_h1);
    unsigned short* hw1 = (unsigned short*)(ws + o_hw1);
    unsigned short* a1w = (unsigned short*)(ws + o_a1w);

    init_k<<<1, 256, 0, stream>>>(curD, curS, nbk);

    int NBLK = (E + CHK - 1) / CHK;   // 782
    int nGm = (n + GROWS - 1) / GROWS; // 1563
    scatter_k<<<NBLK, 256, 0, stream>>>(src, dst, E, curD, curS, pairs, sbuf, nbk);
    gemm_mfma_k<<<nGm, 256, 0, stream>>>(X, W1, B1, h1, n);
    dinvScale_k<<<nbk, 256, 0, stream>>>(sbuf, curS, h1, dinv, hw1, n);
    build_k<<<nbk, 256, 0, stream>>>(pairs, curD, dinv, rowPtr, cntD, col, rsum, n);

    int aggGrid = (n + 3) / 4;
    agg1_k<<<aggGrid, 256, 0, stream>>>(hw1, dinv, col, rowPtr, cntD, a1w, n);
    agg2f_k<<<aggGrid, 256, 0, stream>>>(a1w, dinv, col, rowPtr, cntD, rsum, W2, B2, out, n, NC);
}

// Round 16
// 207.177 us; speedup vs baseline: 1.5562x; 1.3585x over previous
//
#include <hip/hip_runtime.h>
#include <hip/hip_bf16.h>

#define BSH 9
#define BSZ 512    // nodes per bucket
#define CAP 17408  // edge capacity per bucket (mean 16384 + 8 sigma)
#define CHK 4096   // edges per scatter block (16 per thread)

typedef __attribute__((ext_vector_type(8))) short bf16x8;
typedef __attribute__((ext_vector_type(4))) float f32x4;

__device__ __forceinline__ unsigned short f2bf(float f) {  // RN-even fp32->bf16
    unsigned u = __float_as_uint(f);
    u += 0x7fffu + ((u >> 16) & 1u);
    return (unsigned short)(u >> 16);
}
__device__ __forceinline__ float b2f(unsigned short v) {
    return __uint_as_float((unsigned)v << 16);
}

// init bucket cursors to fixed bases
__global__ void init_k(int* __restrict__ curD, int* __restrict__ curS, int nbk) {
    int i = threadIdx.x;
    if (i < nbk) { curD[i] = i * CAP; curS[i] = i * CAP; }
}

// ---------------- fused: MFMA GEMM1 (coop W-frag staging) + bucket-sort scatter -------------
// blocks [0, nGm): gemm (64 rows, 4 waves x one 16-row tile).
// blocks [nGm, nGm+NBLK): scatter.
// pairs packed: (src << 9) | (dst & 511).  sbuf: low 9 bits of src (ushort).

#define GROWS 64
#define GKC 256
#define GSTR 264   // bf16 row stride: 132 dwords == 4 mod 32 -> 2-way banks (free)

__global__ __launch_bounds__(256) void fused_gs_k(
    const float* __restrict__ X, const float* __restrict__ W, const float* __restrict__ B,
    float* __restrict__ H, int n, int nGm,
    const int* __restrict__ src, const int* __restrict__ dst, int E,
    int* __restrict__ curD, int* __restrict__ curS,
    unsigned int* __restrict__ pairs, unsigned short* __restrict__ sbuf, int nbk) {
    __shared__ char smem[GROWS * GSTR * 2];   // 33.8 KB union (gemm tile | scatter stage)
    int t = threadIdx.x;

    if ((int)blockIdx.x < nGm) {
        // ---- GEMM path ----
        unsigned short* xt = (unsigned short*)smem;
        int lane = t & 63, wave = t >> 6;
        int rowBase = blockIdx.x * GROWS;
        int bn = lane & 15;

        // cooperative W -> bf16 frag staging (frag table [16 kt][4 kg][16 bn][8 j] in xt)
        {
            int kt0 = t >> 4, kg0 = (t >> 2) & 3, bn0 = (t & 3) * 4;
            unsigned short frag[4][8];
#pragma unroll
            for (int j = 0; j < 8; ++j) {
                float4 w = *(const float4*)&W[(size_t)(kt0 * 32 + kg0 * 8 + j) * 16 + bn0];
                frag[0][j] = f2bf(w.x); frag[1][j] = f2bf(w.y);
                frag[2][j] = f2bf(w.z); frag[3][j] = f2bf(w.w);
            }
#pragma unroll
            for (int b = 0; b < 4; ++b)
                *(uint4*)&xt[((kt0 * 4 + kg0) * 16 + bn0 + b) * 8] = *(const uint4*)frag[b];
        }
        __syncthreads();
        bf16x8 bw[16];
#pragma unroll
        for (int kt = 0; kt < 16; ++kt)
            bw[kt] = *(const bf16x8*)&xt[(kt * 64 + lane) * 8];
        float bias = B[bn];
        __syncthreads();   // bw reads done before X staging overwrites

        f32x4 acc = {0.f, 0.f, 0.f, 0.f};
        int srow = t >> 4, skq = t & 15;

        for (int ch = 0; ch < 2; ++ch) {
#pragma unroll
            for (int p = 0; p < 4; ++p) {
                int r = p * 16 + srow;
                int gr = rowBase + r;
                const float* xr = &X[(size_t)(gr < n ? gr : n - 1) * 512 + ch * GKC + skq * 4];
#pragma unroll
                for (int q = 0; q < 4; ++q) {
                    float4 v = *(const float4*)&xr[q * 64];
                    ushort4 u;
                    u.x = f2bf(v.x); u.y = f2bf(v.y); u.z = f2bf(v.z); u.w = f2bf(v.w);
                    *(ushort4*)&xt[r * GSTR + skq * 4 + q * 64] = u;
                }
            }
            __syncthreads();

            int rb = (wave * 16 + bn) * GSTR + (lane >> 4) * 8;
#pragma unroll
            for (int kt = 0; kt < 8; ++kt) {
                bf16x8 af = *(const bf16x8*)&xt[rb + kt * 32];
                acc = __builtin_amdgcn_mfma_f32_16x16x32_bf16(af, bw[ch * 8 + kt], acc, 0, 0, 0);
            }
            __syncthreads();
        }

        int r0 = rowBase + wave * 16 + (lane >> 4) * 4;
#pragma unroll
        for (int i = 0; i < 4; ++i) {
            int row = r0 + i;
            if (row < n) H[(size_t)row * 16 + bn] = acc[i] + bias;
        }
    } else {
        // ---- scatter path: register-batched LDS bucket sort -> coalesced burst writes ----
        unsigned int*   stageD = (unsigned int*)smem;             // 4096 * 4B
        unsigned short* stageS = (unsigned short*)(smem + 16384); // 4096 * 2B
        int* cntD  = (int*)(smem + 24576);
        int* cntS  = (int*)(smem + 25600);
        int* rsvD  = (int*)(smem + 26624);
        int* rsvS  = (int*)(smem + 27648);
        int* scanD = (int*)(smem + 28672);
        int* scanS = (int*)(smem + 29696);
        int* ps    = (int*)(smem + 30720);

        int bb = blockIdx.x - nGm;
        int lo = bb * CHK, hi = min(E, lo + CHK);
        bool full = (hi - lo) == CHK;

        cntD[t] = 0; cntS[t] = 0;
        __syncthreads();

        int sv[16], dv[16];
        if (full) {
#pragma unroll
            for (int j = 0; j < 16; j++) {
                int i = lo + t + j * 256;
                sv[j] = src[i]; dv[j] = dst[i];
            }
#pragma unroll
            for (int j = 0; j < 16; j++) {
                atomicAdd(&cntD[dv[j] >> BSH], 1);
                atomicAdd(&cntS[sv[j] >> BSH], 1);
            }
        } else {
            for (int i = lo + t; i < hi; i += 256) {
                atomicAdd(&cntD[dst[i] >> BSH], 1);
                atomicAdd(&cntS[src[i] >> BSH], 1);
            }
        }
        __syncthreads();
        int vD = cntD[t];
        ps[t] = vD; __syncthreads();
        for (int o = 1; o < 256; o <<= 1) {
            int u = (t >= o) ? ps[t - o] : 0; __syncthreads();
            ps[t] += u; __syncthreads();
        }
        scanD[t] = ps[t] - vD;
        if (t < nbk && vD) rsvD[t] = atomicAdd(&curD[t], vD);
        __syncthreads();
        int vS = cntS[t];
        ps[t] = vS; __syncthreads();
        for (int o = 1; o < 256; o <<= 1) {
            int u = (t >= o) ? ps[t - o] : 0; __syncthreads();
            ps[t] += u; __syncthreads();
        }
        scanS[t] = ps[t] - vS;
        if (t < nbk && vS) rsvS[t] = atomicAdd(&curS[t], vS);
        cntD[t] = 0; cntS[t] = 0;
        __syncthreads();
        if (full) {
#pragma unroll
            for (int j = 0; j < 16; j++) {
                int s = sv[j], d = dv[j];
                int bd = d >> BSH;
                int pd = scanD[bd] + atomicAdd(&cntD[bd], 1);
                stageD[pd] = ((unsigned int)s << BSH) | (unsigned int)(d & (BSZ - 1));
                int bs = s >> BSH;
                int pp = scanS[bs] + atomicAdd(&cntS[bs], 1);
                stageS[pp] = (unsigned short)(s & (BSZ - 1));
            }
        } else {
            for (int i = lo + t; i < hi; i += 256) {
                int s = src[i], d = dst[i];
                int bd = d >> BSH;
                int pd = scanD[bd] + atomicAdd(&cntD[bd], 1);
                stageD[pd] = ((unsigned int)s << BSH) | (unsigned int)(d & (BSZ - 1));
                int bs = s >> BSH;
                int pp = scanS[bs] + atomicAdd(&cntS[bs], 1);
                stageS[pp] = (unsigned short)(s & (BSZ - 1));
            }
        }
        __syncthreads();
        int wave = t >> 6, lane = t & 63;
        for (int b = wave; b < nbk; b += 4) {
            int st = scanD[b], len = cntD[b], g = rsvD[b];
            for (int j = lane; j < len; j += 64) pairs[g + j] = stageD[st + j];
        }
        for (int b = wave; b < nbk; b += 4) {
            int st = scanS[b], len = cntS[b], g = rsvS[b];
            for (int j = lane; j < len; j += 64) sbuf[g + j] = stageS[st + j];
        }
    }
}

// ---------------- dinv (src-degree) + scale h1 -> bf16 hw1 (hw1 = dinv * h1) ----------------

__global__ __launch_bounds__(256) void dinvScale_k(const unsigned short* __restrict__ sbuf,
                                                   const int* __restrict__ curS,
                                                   const float* __restrict__ h1,
                                                   float* __restrict__ dinv,
                                                   unsigned short* __restrict__ hw1, int n) {
    __shared__ int cnt[BSZ];
    __shared__ float dl[BSZ];
    int b = blockIdx.x, t = threadIdx.x;
    cnt[t] = 0; cnt[t + 256] = 0;
    __syncthreads();
    int lo = b * CAP, hi = curS[b];
    for (int i = lo + t; i < hi; i += 256) atomicAdd(&cnt[sbuf[i]], 1);
    __syncthreads();
    int n0 = b * BSZ + t, n1 = n0 + 256;
    float d0 = rsqrtf((float)(1 + cnt[t]));
    float d1 = rsqrtf((float)(1 + cnt[t + 256]));
    dl[t] = d0; dl[t + 256] = d1;
    if (n0 < n) dinv[n0] = d0;
    if (n1 < n) dinv[n1] = d1;
    __syncthreads();
    int rows = min(BSZ, n - b * BSZ);
    int lim4 = rows * 4;
    size_t base = (size_t)b * BSZ * 16;
#pragma unroll
    for (int j = 0; j < 8; j++) {
        int i4 = j * 256 + t;
        if (i4 < lim4) {
            float4 v = *(const float4*)&h1[base + (size_t)i4 * 4];
            float d = dl[i4 >> 2];
            ushort4 u;
            u.x = f2bf(v.x * d); u.y = f2bf(v.y * d);
            u.z = f2bf(v.z * d); u.w = f2bf(v.w * d);
            *(ushort4*)&hw1[base + (size_t)i4 * 4] = u;
        }
    }
}

// ---------------- bucket-centric aggregation (INT fixed-point LDS atomics, native ds_add) ---
// One block per dst-bucket; iacc[512][16] int (val * 2^16) in LDS; edges streamed from pairs.
// LAYER 1: epilogue = self + relu + premult + bf16 store + rowsum.
// LAYER 2: epilogue = self + logits + log_softmax.

#define FPS 65536.f
#define FPI (1.f / 65536.f)

template <int LAYER>
__global__ __launch_bounds__(1024) void aggB_k(
    const unsigned int* __restrict__ pairs, const int* __restrict__ curD,
    const unsigned short* __restrict__ HW, const float* __restrict__ dinv,
    float* __restrict__ rowsum, const float* __restrict__ W2,
    const float* __restrict__ B2, unsigned short* __restrict__ outA,
    float* __restrict__ outF, int n, int nc) {
    __shared__ int iacc[BSZ * 16];        // 32 KB
    __shared__ unsigned int rsl[BSZ];     // 2 KB (layer 1)
    int b = blockIdx.x, t = threadIdx.x;
    for (int i = t; i < BSZ * 16; i += 1024) iacc[i] = 0;
    if (LAYER == 1)
        for (int i = t; i < BSZ; i += 1024) rsl[i] = 0u;
    __syncthreads();

    int lo = b * CAP, hi = curD[b];
    int q = t & 3;
    int i = lo + (t >> 2);
    for (; i + 256 < hi; i += 512) {   // 2 edges in flight per lane
        unsigned int p0 = pairs[i], p1 = pairs[i + 256];
        int s0 = p0 >> BSH, l0 = p0 & (BSZ - 1);
        int s1 = p1 >> BSH, l1 = p1 & (BSZ - 1);
        ushort4 u0 = *(const ushort4*)&HW[(size_t)s0 * 16 + q * 4];
        ushort4 u1 = *(const ushort4*)&HW[(size_t)s1 * 16 + q * 4];
        int* a0 = &iacc[l0 * 16 + q * 4];
        atomicAdd(&a0[0], __float2int_rn(b2f(u0.x) * FPS));
        atomicAdd(&a0[1], __float2int_rn(b2f(u0.y) * FPS));
        atomicAdd(&a0[2], __float2int_rn(b2f(u0.z) * FPS));
        atomicAdd(&a0[3], __float2int_rn(b2f(u0.w) * FPS));
        int* a1 = &iacc[l1 * 16 + q * 4];
        atomicAdd(&a1[0], __float2int_rn(b2f(u1.x) * FPS));
        atomicAdd(&a1[1], __float2int_rn(b2f(u1.y) * FPS));
        atomicAdd(&a1[2], __float2int_rn(b2f(u1.z) * FPS));
        atomicAdd(&a1[3], __float2int_rn(b2f(u1.w) * FPS));
        if (LAYER == 1 && q == 0) {
            atomicAdd(&rsl[l0], (unsigned int)(dinv[s0] * FPS + 0.5f));
            atomicAdd(&rsl[l1], (unsigned int)(dinv[s1] * FPS + 0.5f));
        }
    }
    if (i < hi) {
        unsigned int p0 = pairs[i];
        int s0 = p0 >> BSH, l0 = p0 & (BSZ - 1);
        ushort4 u0 = *(const ushort4*)&HW[(size_t)s0 * 16 + q * 4];
        int* a0 = &iacc[l0 * 16 + q * 4];
        atomicAdd(&a0[0], __float2int_rn(b2f(u0.x) * FPS));
        atomicAdd(&a0[1], __float2int_rn(b2f(u0.y) * FPS));
        atomicAdd(&a0[2], __float2int_rn(b2f(u0.z) * FPS));
        atomicAdd(&a0[3], __float2int_rn(b2f(u0.w) * FPS));
        if (LAYER == 1 && q == 0) atomicAdd(&rsl[l0], (unsigned int)(dinv[s0] * FPS + 0.5f));
    }
    __syncthreads();

    if (LAYER == 1) {
        int ln = t >> 1, f0 = (t & 1) * 8;
        int node = b * BSZ + ln;
        if (node < n) {
            float dd = dinv[node];
            const ushort4* sp = (const ushort4*)&HW[(size_t)node * 16 + f0];
            ushort4 s0 = sp[0], s1 = sp[1];
            const int* ap = &iacc[ln * 16 + f0];
            ushort4 o0, o1;
            o0.x = f2bf(dd * fmaxf(dd * ((float)ap[0] * FPI + b2f(s0.x)), 0.f));
            o0.y = f2bf(dd * fmaxf(dd * ((float)ap[1] * FPI + b2f(s0.y)), 0.f));
            o0.z = f2bf(dd * fmaxf(dd * ((float)ap[2] * FPI + b2f(s0.z)), 0.f));
            o0.w = f2bf(dd * fmaxf(dd * ((float)ap[3] * FPI + b2f(s0.w)), 0.f));
            o1.x = f2bf(dd * fmaxf(dd * ((float)ap[4] * FPI + b2f(s1.x)), 0.f));
            o1.y = f2bf(dd * fmaxf(dd * ((float)ap[5] * FPI + b2f(s1.y)), 0.f));
            o1.z = f2bf(dd * fmaxf(dd * ((float)ap[6] * FPI + b2f(s1.z)), 0.f));
            o1.w = f2bf(dd * fmaxf(dd * ((float)ap[7] * FPI + b2f(s1.w)), 0.f));
            ushort4* op = (ushort4*)&outA[(size_t)node * 16 + f0];
            op[0] = o0; op[1] = o1;
            if (f0 == 0) rowsum[node] = dd * (dd + (float)rsl[ln] * FPI);
        }
    } else {
        int wave = t >> 6, lane = t & 63;
        int node0 = b * BSZ;
        int nodeEnd = min(node0 + BSZ, n);
        for (int node = node0 + wave; node < nodeEnd; node += 16) {
            int ln = node - node0;
            float dd = dinv[node];
            float f[16];
            const ushort4* sp = (const ushort4*)&HW[(size_t)node * 16];
#pragma unroll
            for (int g = 0; g < 4; g++) {
                ushort4 u = sp[g];
                f[g * 4 + 0] = dd * ((float)iacc[ln * 16 + g * 4 + 0] * FPI + b2f(u.x));
                f[g * 4 + 1] = dd * ((float)iacc[ln * 16 + g * 4 + 1] * FPI + b2f(u.y));
                f[g * 4 + 2] = dd * ((float)iacc[ln * 16 + g * 4 + 2] * FPI + b2f(u.z));
                f[g * 4 + 3] = dd * ((float)iacc[ln * 16 + g * 4 + 3] * FPI + b2f(u.w));
            }
            float logit = -1e30f;
            if (lane < nc) {
                logit = rowsum[node] * B2[lane];
#pragma unroll
                for (int k = 0; k < 16; k++) logit = fmaf(f[k], W2[k * nc + lane], logit);
            }
            float m = logit;
#pragma unroll
            for (int off = 1; off < 64; off <<= 1) m = fmaxf(m, __shfl_xor(m, off, 64));
            float e = (lane < nc) ? __expf(logit - m) : 0.f;
            float s = e;
#pragma unroll
            for (int off = 1; off < 64; off <<= 1) s += __shfl_xor(s, off, 64);
            if (lane < nc) outF[(size_t)node * nc + lane] = logit - m - __logf(s);
        }
    }
}

// ---------------- launch ----------------

extern "C" void kernel_launch(void* const* d_in, const int* in_sizes, int n_in,
                              void* d_out, int out_size, void* d_ws, size_t ws_size,
                              hipStream_t stream) {
    const float* X  = (const float*)d_in[0];
    const int*   EI = (const int*)d_in[1];
    const float* W1 = (const float*)d_in[2];
    const float* B1 = (const float*)d_in[3];
    const float* W2 = (const float*)d_in[4];
    const float* B2 = (const float*)d_in[5];
    float* out = (float*)d_out;

    int NH = in_sizes[3];            // 16
    int NC = in_sizes[5];            // 40
    int NF = in_sizes[2] / NH;       // 512
    int n  = in_sizes[0] / NF;       // 100000
    int E  = in_sizes[1] / 2;        // 3200000
    const int* src = EI;
    const int* dst = EI + E;
    int nbk = (n + BSZ - 1) >> BSH;  // 196

    char* ws = (char*)d_ws;
    size_t o = 0;
    auto alloc = [&](size_t bytes) { size_t r = o; o = (o + bytes + 255) & ~(size_t)255; return r; };
    size_t o_dinv   = alloc((size_t)n * 4);
    size_t o_rsum   = alloc((size_t)n * 4);
    size_t o_curD   = alloc(1024);
    size_t o_curS   = alloc(1024);
    size_t o_pairs  = alloc((size_t)nbk * CAP * 4);
    size_t o_sbuf   = alloc((size_t)nbk * CAP * 2);
    size_t o_h1     = alloc((size_t)n * 16 * 4);
    size_t o_hw1    = alloc((size_t)n * 16 * 2);
    size_t o_a1w    = alloc((size_t)n * 16 * 2);

    float* dinv  = (float*)(ws + o_dinv);
    float* rsum  = (float*)(ws + o_rsum);
    int* curD    = (int*)(ws + o_curD);
    int* curS    = (int*)(ws + o_curS);
    unsigned int* pairs   = (unsigned int*)(ws + o_pairs);
    unsigned short* sbuf  = (unsigned short*)(ws + o_sbuf);
    float* h1    = (float*)(ws + o_h1);
    unsigned short* hw1 = (unsigned short*)(ws + o_hw1);
    unsigned short* a1w = (unsigned short*)(ws + o_a1w);

    init_k<<<1, 256, 0, stream>>>(curD, curS, nbk);

    int NBLK = (E + CHK - 1) / CHK;      // 782
    int nGm = (n + GROWS - 1) / GROWS;   // 1563
    fused_gs_k<<<nGm + NBLK, 256, 0, stream>>>(X, W1, B1, h1, n, nGm,
                                               src, dst, E, curD, curS,
                                               pairs, sbuf, nbk);
    dinvScale_k<<<nbk, 256, 0, stream>>>(sbuf, curS, h1, dinv, hw1, n);

    aggB_k<1><<<nbk, 1024, 0, stream>>>(pairs, curD, hw1, dinv, rsum,
                                        nullptr, nullptr, a1w, nullptr, n, NC);
    aggB_k<2><<<nbk, 1024, 0, stream>>>(pairs, curD, a1w, dinv, rsum,
                                        W2, B2, nullptr, out, n, NC);
}